// Round 10
// baseline (162.479 us; speedup 1.0000x reference)
//
#include <hip/hip_runtime.h>
#include <hip/hip_bf16.h>

// y = x @ W^T + b ; x:(16,8192,256) f32, W:(256,256) f32, b:(256,) f32, out f32
// M=131072, N=256, K=256. Memory-bound (floor ~41us with measured 68MB L3-miss reads).
// R10 = R8 + 2-TILE BARRIER PERIODS (4 LDS buffers):
//   stage pair at period START (loads issued one FULL period earlier -> HBM
//   queuing latency covered), issue next pair's loads, compute+store 2 tiles.
//   Barriers halved (8->4 per block). Tests: latency-window vs throughput-bound.
// History: R2 grid 1024 hurt; R3 transposed loads = VMEM death; R5 builtin-nt
//   stores +3us (keep); R7 partial-line dwordx4 = write amp; R8 lgkm-only
//   barrier = null (drains free); R9 sc0sc1nt = +10% WRITE amp (revert).

typedef __attribute__((ext_vector_type(8))) short bf16x8;
typedef __attribute__((ext_vector_type(16))) float f32x16;

__device__ __forceinline__ short f2bf(float f) {
    __hip_bfloat16 h = __float2bfloat16(f);   // RTNE
    return *reinterpret_cast<short*>(&h);
}

#define BM   32
#define LDSK 264   // 256 + 8 pad: 528B row stride -> conflict-free b128 frag reads

__global__ __launch_bounds__(512, 4)
void rac_linear_kernel(const float* __restrict__ x,
                       const float* __restrict__ w,
                       const float* __restrict__ bias,
                       float* __restrict__ out,
                       int tiles_per_block)
{
    __shared__ short lds[4][BM * LDSK];   // 4 x 16.5 KB = 66 KB (2 blocks/CU)

    const int tid  = threadIdx.x;
    const int lane = tid & 63;
    const int wv   = tid >> 6;        // 0..7: N-wave, owns cols [wv*32, wv*32+32)
    const int l31  = lane & 31;
    const int lh   = lane >> 5;       // 0/1: k-half of the fragment
    const int srow = tid >> 6;        // staging row base
    const int skk  = (tid & 63) * 4;  // staging k offset

    // ---- B prologue: W[n][k] -> per-wave bf16 register fragments ----
    // B frag layout (32x32x16): col = lane&31 (n), k = (lane>>5)*8 + j
    bf16x8 bfrag[16];
    {
        const int   wrow = wv * 32 + l31;                 // n index
        const float* wb  = w + (size_t)wrow * 256 + lh * 8;
        #pragma unroll
        for (int ks = 0; ks < 16; ++ks) {
            const float4 lo = *reinterpret_cast<const float4*>(wb + ks * 16);
            const float4 hi = *reinterpret_cast<const float4*>(wb + ks * 16 + 4);
            bf16x8 b;
            b[0]=f2bf(lo.x); b[1]=f2bf(lo.y); b[2]=f2bf(lo.z); b[3]=f2bf(lo.w);
            b[4]=f2bf(hi.x); b[5]=f2bf(hi.y); b[6]=f2bf(hi.z); b[7]=f2bf(hi.w);
            bfrag[ks] = b;
        }
    }
    const float bval = bias[wv * 32 + l31];

    const int t0 = blockIdx.x * tiles_per_block;

    float4 vA[4], vB[4];

    auto loadT = [&](float4* v, int g) {
        const float4* src = reinterpret_cast<const float4*>(x + (size_t)g * (BM * 256));
        #pragma unroll
        for (int i = 0; i < 4; ++i) v[i] = src[i * 512 + tid];   // fully coalesced
    };
    auto stageT = [&](const float4* v, int b) {
        #pragma unroll
        for (int i = 0; i < 4; ++i) {
            short4 s;
            s.x=f2bf(v[i].x); s.y=f2bf(v[i].y); s.z=f2bf(v[i].z); s.w=f2bf(v[i].w);
            *reinterpret_cast<short4*>(&lds[b][(i * 8 + srow) * LDSK + skk]) = s;
        }
    };
    auto compT = [&](int b, int g) {
        f32x16 acc;
        #pragma unroll
        for (int r = 0; r < 16; ++r) acc[r] = bval;
        const short* abase = &lds[b][l31 * LDSK + lh * 8];
        #pragma unroll
        for (int ks = 0; ks < 16; ++ks) {
            bf16x8 a = *reinterpret_cast<const bf16x8*>(abase + ks * 16);
            acc = __builtin_amdgcn_mfma_f32_32x32x16_bf16(a, bfrag[ks], acc, 0, 0, 0);
        }
        // C layout: col=lane&31, row=(r&3)+8*(r>>2)+4*(lane>>5).
        // 32 lanes sweep one row -> full 128B lines per store (R7 lesson). nt: no reuse.
        float* ob = out + (size_t)g * (BM * 256) + wv * 32 + l31;
        const int rhi = lh * 4;
        #pragma unroll
        for (int r = 0; r < 16; ++r) {
            const int row = (r & 3) + 8 * (r >> 2) + rhi;
            __builtin_nontemporal_store(acc[r], &ob[(size_t)row * 256]);
        }
    };

    // ---- prologue: stage tiles 0,1; preload tiles 2,3 ----
    loadT(vA, t0);     loadT(vB, t0 + 1);
    stageT(vA, 0);     stageT(vB, 1);
    loadT(vA, t0 + 2); loadT(vB, t0 + 3);
    __syncthreads();   // full drain once at startup

    const int NP = tiles_per_block >> 1;   // 2 tiles per period
    for (int p = 0; p < NP; ++p) {
        const int l0 = 2 * p;                 // local tile index of first tile
        const int c0 = (p & 1) * 2;           // compute buffers {c0, c0+1}
        const int n0 = ((p + 1) & 1) * 2;     // stage buffers {n0, n0+1}

        // 1. stage next pair (v loaded one FULL period ago -> latency covered).
        //    Overwrites bufs computed-from in period p-1 (tail barrier of p-1
        //    guarantees all waves finished reading them).
        if (l0 + 2 < tiles_per_block) { stageT(vA, n0); stageT(vB, n0 + 1); }

        // 2. issue loads for the pair after next (consumed at start of p+1)
        if (l0 + 4 < tiles_per_block) { loadT(vA, t0 + l0 + 4); loadT(vB, t0 + l0 + 5); }

        // 3. compute + store both tiles of this period
        compT(c0,     t0 + l0);
        compT(c0 + 1, t0 + l0 + 1);

        // 4. LDS-visibility barrier only (R8: drain behavior is perf-neutral)
        if (p + 1 < NP)
            asm volatile("s_waitcnt lgkmcnt(0)\n\ts_barrier" ::: "memory");
    }
}

extern "C" void kernel_launch(void* const* d_in, const int* in_sizes, int n_in,
                              void* d_out, int out_size, void* d_ws, size_t ws_size,
                              hipStream_t stream)
{
    const float* x    = (const float*)d_in[0];
    const float* w    = (const float*)d_in[1];
    const float* bias = (const float*)d_in[2];
    float* out        = (float*)d_out;

    const int M      = in_sizes[0] / 256;   // 131072 rows
    const int ntiles = M / BM;              // 4096
    const int grid   = 512;                 // 2 blocks/CU
    const int tpb    = ntiles / grid;       // 8 tiles per block (4 periods)

    rac_linear_kernel<<<grid, 512, 0, stream>>>(x, w, bias, out, tpb);
}

// Round 11
// 66.314 us; speedup vs baseline: 2.4501x; 2.4501x over previous
//
#include <hip/hip_runtime.h>
#include <hip/hip_bf16.h>

// y = x @ W^T + b ; x:(16,8192,256) f32, W:(256,256) f32, b:(256,) f32, out f32
// M=131072, N=256, K=256. Memory-bound.
// R11 = R8 (best-equal, 58.8us) + ONE change: NON-TEMPORAL x LOADS.
// Theory: x/out contend for L3; the 68MB of x that miss are an LRU-scattered
//   subset -> DRAM page locality destroyed -> 3.4 TB/s vs copy's 6.3. nt loads
//   make x a pure sequential HBM stream (134MB, no L3 alloc) like m13's copy.
// History: R2 more blocks hurt; R3 transposed loads = VMEM death; R4/R10
//   stage-early restructures -> wave drift -> nt partial-line write amp
//   (R10: WRITE 343MB!) -> per-tile lockstep barrier is PROTECTIVE;
//   R5 nt stores +3us (keep); R7 lane-owns-row stores = write amp;
//   R8 lgkm-only barrier = null (drains free); R9 sc0sc1 = +10% write amp.

typedef __attribute__((ext_vector_type(8))) short bf16x8;
typedef __attribute__((ext_vector_type(16))) float f32x16;
typedef __attribute__((ext_vector_type(4)))  float f32x4;

__device__ __forceinline__ short f2bf(float f) {
    __hip_bfloat16 h = __float2bfloat16(f);   // RTNE
    return *reinterpret_cast<short*>(&h);
}

#define BM   32
#define LDSK 264   // 256 + 8 pad: 528B row stride -> conflict-free b128 frag reads

__global__ __launch_bounds__(512, 4)
void rac_linear_kernel(const float* __restrict__ x,
                       const float* __restrict__ w,
                       const float* __restrict__ bias,
                       float* __restrict__ out,
                       int tiles_per_block)
{
    __shared__ short lds[2][BM * LDSK];   // 2 x 16.5 KB

    const int tid  = threadIdx.x;
    const int lane = tid & 63;
    const int wv   = tid >> 6;        // 0..7: N-wave, owns cols [wv*32, wv*32+32)
    const int l31  = lane & 31;
    const int lh   = lane >> 5;       // 0/1: k-half of the fragment

    // ---- B prologue: W[n][k] -> per-wave bf16 register fragments ----
    // B frag layout (32x32x16): col = lane&31 (n), k = (lane>>5)*8 + j
    bf16x8 bfrag[16];
    {
        const int   wrow = wv * 32 + l31;                 // n index
        const float* wb  = w + (size_t)wrow * 256 + lh * 8;
        #pragma unroll
        for (int ks = 0; ks < 16; ++ks) {
            const float4 lo = *reinterpret_cast<const float4*>(wb + ks * 16);
            const float4 hi = *reinterpret_cast<const float4*>(wb + ks * 16 + 4);
            bf16x8 b;
            b[0]=f2bf(lo.x); b[1]=f2bf(lo.y); b[2]=f2bf(lo.z); b[3]=f2bf(lo.w);
            b[4]=f2bf(hi.x); b[5]=f2bf(hi.y); b[6]=f2bf(hi.z); b[7]=f2bf(hi.w);
            bfrag[ks] = b;
        }
    }
    const float bval = bias[wv * 32 + l31];

    const int t0 = blockIdx.x * tiles_per_block;

    f32x4 v[4];   // staging registers (one BM x 256 f32 tile = 64 B/thread)

    auto loadT = [&](int g) {   // nt: x is stream-once, keep it OUT of L3
        const f32x4* src = reinterpret_cast<const f32x4*>(x + (size_t)g * (BM * 256));
        #pragma unroll
        for (int i = 0; i < 4; ++i)
            v[i] = __builtin_nontemporal_load(src + i * 512 + tid);
    };

    // prologue: load + stage tile t0 into buf 0
    {
        loadT(t0);
        #pragma unroll
        for (int i = 0; i < 4; ++i) {
            const int row = i * 8 + (tid >> 6);      // elem = i*2048 + tid*4
            const int k   = (tid & 63) * 4;
            short4 s;
            s.x=f2bf(v[i][0]); s.y=f2bf(v[i][1]); s.z=f2bf(v[i][2]); s.w=f2bf(v[i][3]);
            *reinterpret_cast<short4*>(&lds[0][row * LDSK + k]) = s;
        }
    }

    for (int t = 0; t < tiles_per_block; ++t) {
        const int buf  = t & 1;
        const int tile = t0 + t;

        // LDS-visibility barrier (R8: drain-vs-not perf-neutral; keeps waves
        // lockstep per tile -> protects nt-store line merging, R10 lesson)
        asm volatile("s_waitcnt lgkmcnt(0)\n\ts_barrier" ::: "memory");

        // issue next tile's global loads early (latency hidden under compute)
        if (t + 1 < tiles_per_block) loadT(tile + 1);

        // ---- compute: 16 K-steps of mfma_f32_32x32x16_bf16 ----
        f32x16 acc;
        #pragma unroll
        for (int r = 0; r < 16; ++r) acc[r] = bval;

        // A frag layout: row = lane&31 (m), k = (lane>>5)*8 + j
        const short* abase = &lds[buf][l31 * LDSK + lh * 8];
        #pragma unroll
        for (int ks = 0; ks < 16; ++ks) {
            bf16x8 a = *reinterpret_cast<const bf16x8*>(abase + ks * 16);
            acc = __builtin_amdgcn_mfma_f32_32x32x16_bf16(a, bfrag[ks], acc, 0, 0, 0);
        }

        // ---- epilogue: C layout col=lane&31, row=(r&3)+8*(r>>2)+4*(lane>>5) ----
        // 32 lanes sweep one output row -> full 128B line coverage per instr
        // (R7 lesson). nt: out has no reuse.
        {
            float* ob = out + (size_t)tile * (BM * 256) + wv * 32 + l31;
            const int rhi = lh * 4;
            #pragma unroll
            for (int r = 0; r < 16; ++r) {
                const int row = (r & 3) + 8 * (r >> 2) + rhi;
                __builtin_nontemporal_store(acc[r], &ob[(size_t)row * 256]);
            }
        }

        // stage next tile into the other buffer (safe: all waves past barrier)
        if (t + 1 < tiles_per_block) {
            #pragma unroll
            for (int i = 0; i < 4; ++i) {
                const int row = i * 8 + (tid >> 6);
                const int k   = (tid & 63) * 4;
                short4 s;
                s.x=f2bf(v[i][0]); s.y=f2bf(v[i][1]); s.z=f2bf(v[i][2]); s.w=f2bf(v[i][3]);
                *reinterpret_cast<short4*>(&lds[buf ^ 1][row * LDSK + k]) = s;
            }
        }
    }
}

extern "C" void kernel_launch(void* const* d_in, const int* in_sizes, int n_in,
                              void* d_out, int out_size, void* d_ws, size_t ws_size,
                              hipStream_t stream)
{
    const float* x    = (const float*)d_in[0];
    const float* w    = (const float*)d_in[1];
    const float* bias = (const float*)d_in[2];
    float* out        = (float*)d_out;

    const int M      = in_sizes[0] / 256;   // 131072 rows
    const int ntiles = M / BM;              // 4096
    const int grid   = 512;                 // 2 blocks/CU
    const int tpb    = ntiles / grid;       // 8 tiles per block

    rac_linear_kernel<<<grid, 512, 0, stream>>>(x, w, bias, out, tpb);
}